// Round 2
// baseline (2749.702 us; speedup 1.0000x reference)
//
#include <hip/hip_runtime.h>

#define NN 8192
#define NSB 16      // super-blocks of 512
#define SBS 512
#define SUB 64
#define LOG2E 1.44269504088896f

// flag indices (ints at start of ws)
#define F_SUBDONE 0
#define F_CRIT(kc,cw) (1 + (kc)*8 + (cw))
#define F_SLOW(kc) (129 + (kc))
#define NFLAGS 160

// float offsets into ws (floats), after 256-int flag area
#define OFF_ACCC 256                    // [2][SBS]
#define OFF_CSLOW (256 + 2*SBS)         // [4][NN]
#define OFF_SARR (256 + 2*SBS + 4*NN)   // [NN]

__device__ __forceinline__ float bcastf(float v, int lane) {
    return __int_as_float(__builtin_amdgcn_readlane(__float_as_int(v), lane));
}
__device__ __forceinline__ void spin_ge(int* p, int want, int slp) {
    while (__hip_atomic_load(p, __ATOMIC_RELAXED, __HIP_MEMORY_SCOPE_AGENT) < want) {
        if (slp) __builtin_amdgcn_s_sleep(1);
    }
    __builtin_amdgcn_fence(__ATOMIC_ACQUIRE, "agent");
}
__device__ __forceinline__ void st_rel(int* p, int v) {
    __hip_atomic_store(p, v, __ATOMIC_RELEASE, __HIP_MEMORY_SCOPE_AGENT);
}
__device__ __forceinline__ float ldf(const float* p) {
    return __hip_atomic_load(p, __ATOMIC_RELAXED, __HIP_MEMORY_SCOPE_AGENT);
}
__device__ __forceinline__ void stf(float* p, float v) {
    __hip_atomic_store(p, v, __ATOMIC_RELAXED, __HIP_MEMORY_SCOPE_AGENT);
}

__global__ void init_flags(int* flags) {
    int t = threadIdx.x;
    if (t < NFLAGS) flags[t] = 0;
}

// ---------------- solver: 1 WG, 8 waves, wave w owns cols [w*64, w*64+64) ----------------
__device__ void solver_fn(const float* __restrict__ W, const float* __restrict__ b,
                          const float* __restrict__ x, float* ws_f, int* flags,
                          float* __restrict__ out) {
    __shared__ float sscaled[SBS];   // LOG2E * s for the current super-block
    const int tid = threadIdx.x;
    const int w = tid >> 6, l = tid & 63;
    float* accC  = ws_f + OFF_ACCC;
    float* cslow = ws_f + OFF_CSLOW;
    float* s_arr = ws_f + OFF_SARR;
    const float x0 = x[0], x1 = x[1];
    float s_keep = 0.0f;

    #pragma unroll 1
    for (int kc = 0; kc < NSB; ++kc) {
        const int J0  = kc * SBS;
        const int col = J0 + w * SUB + l;

        // ---- prefetch (static addresses, issued before flag waits) ----
        float wdiag[SUB];
        #pragma unroll
        for (int j = 0; j < SUB; ++j)
            wdiag[j] = (j < l) ? W[(size_t)(J0 + w*SUB + j) * NN + col] : 0.0f;
        float panP[SUB];
        if (kc > 0) {
            const int r0 = J0 - SUB;   // prev block, sub-block 7 rows
            #pragma unroll
            for (int i = 0; i < SUB; ++i)
                panP[i] = W[(size_t)(r0 + i) * NN + col];
        }
        const float bb = b[col];

        // ---- wait for workers feeding this block ----
        if (kc >= 1) spin_ge(&flags[F_CRIT(kc, w)], 1, 0);
        if (kc >= 2) spin_ge(&flags[F_SLOW(kc)], 4, 0);

        float base = bb;
        if (kc >= 1) base += ldf(&accC[(kc & 1) * SBS + w*SUB + l]);
        if (kc >= 2) {
            #pragma unroll
            for (int q = 0; q < 4; ++q) base += ldf(&cslow[q * NN + col]);
        }
        float acc = base * LOG2E;
        if (kc > 0) {   // fold prev block's sub-7 rows (still in LDS, scaled)
            #pragma unroll
            for (int i = 0; i < SUB; ++i)
                acc += panP[i] * sscaled[7*SUB + i];
        }
        #pragma unroll
        for (int j = 0; j < SUB; ++j) wdiag[j] *= LOG2E;

        float pan[SUB];
        if (w > 0) {
            #pragma unroll
            for (int i = 0; i < SUB; ++i)
                pan[i] = W[(size_t)(J0 + i) * NN + col];
        }

        #pragma unroll 1
        for (int m = 0; m < 8; ++m) {
            if (w == m) {
                const bool first = (kc == 0) && (w == 0);
                float smine = 0.0f;
                #pragma unroll
                for (int j = 0; j < SUB; ++j) {
                    const float pre = bcastf(acc, j);
                    float s;
                    if (first && j == 0)      s = x0;
                    else if (first && j == 1) s = x1;
                    else s = __builtin_amdgcn_rcpf(1.0f + __builtin_amdgcn_exp2f(-pre));
                    acc += wdiag[j] * s;
                    if (l == j) smine = s;
                }
                stf(&s_arr[col], smine);            // global publish (drains in background)
                sscaled[w*SUB + l] = smine * LOG2E; // LDS publish
                s_keep = smine;
                asm volatile("s_waitcnt lgkmcnt(0)" ::: "memory");
                __builtin_amdgcn_sched_barrier(0);
            }
            __builtin_amdgcn_s_barrier();
            asm volatile("" ::: "memory");
            if (w == m && l == 0)
                st_rel(&flags[F_SUBDONE], kc*8 + m + 1);  // after barrier: free (hidden)
            if (m < w) {
                #pragma unroll
                for (int i = 0; i < SUB; ++i)
                    acc += pan[i] * sscaled[m*SUB + i];
                if (m + 1 < w) {
                    const int r0 = J0 + (m+1)*SUB;
                    #pragma unroll
                    for (int i = 0; i < SUB; ++i)
                        pan[i] = W[(size_t)(r0 + i) * NN + col];   // next chain hides latency
                }
            }
        }
    }
    if (w == 7 && l == 63) out[0] = s_keep;
}

// ---------------- crit workers: panel kc -> kc+1, rows 0..447 (progressive) ----------------
__device__ void crit_fn(const float* __restrict__ W, float* ws_f, int* flags, int cw) {
    __shared__ float red[8][SUB];
    const int tid = threadIdx.x;
    const int l = tid & 63, g = tid >> 6;   // col lane, row-group (wave)
    float* accC  = ws_f + OFF_ACCC;
    float* s_arr = ws_f + OFF_SARR;

    #pragma unroll 1
    for (int kc = 0; kc < NSB - 1; ++kc) {
        const int tcol = (kc+1)*SBS + cw*SUB + l;
        float part = 0.0f;
        #pragma unroll 1
        for (int m = 0; m < 7; ++m) {       // subs 0..6 only; sub 7 folded in by solver
            const int r0 = kc*SBS + m*SUB + g*8;
            float wv[8];
            #pragma unroll
            for (int r = 0; r < 8; ++r)
                wv[r] = W[(size_t)(r0 + r) * NN + tcol];   // prefetch before spin
            spin_ge(&flags[F_SUBDONE], kc*8 + m + 1, 1);
            #pragma unroll
            for (int r = 0; r < 8; ++r)
                part += wv[r] * ldf(&s_arr[r0 + r]);
        }
        red[g][l] = part;
        __syncthreads();
        if (g == 0) {
            float sum = 0.0f;
            #pragma unroll
            for (int gg = 0; gg < 8; ++gg) sum += red[gg][l];
            stf(&accC[((kc+1) & 1) * SBS + cw*SUB + l], sum);
        }
        if (tid == 0) st_rel(&flags[F_CRIT(kc+1, cw)], 1);  // same wave as stores
        __syncthreads();
    }
}

// ---------------- slow owners: (block kt, quarter qh) accumulate panels 0..kt-2 ----------------
__device__ void slow_fn(const float* __restrict__ W, float* ws_f, int* flags,
                        int kt, int qh) {
    __shared__ float s_lds[128];
    const int tid = threadIdx.x;
    const int col = kt*SBS + tid;
    float* cslow = ws_f + OFF_CSLOW;
    float* s_arr = ws_f + OFF_SARR;
    float c = 0.0f;

    #pragma unroll 1
    for (int kc2 = 0; kc2 <= kt - 2; ++kc2) {
        spin_ge(&flags[F_SUBDONE], (kc2+1)*8, 1);
        __syncthreads();   // protect s_lds reuse
        if (tid < 128) s_lds[tid] = ldf(&s_arr[kc2*SBS + qh*128 + tid]);
        __syncthreads();
        const float* wp = W + (size_t)(kc2*SBS + qh*128) * NN + col;
        #pragma unroll 8
        for (int i = 0; i < 128; ++i)
            c += wp[(size_t)i * NN] * s_lds[i];
    }
    stf(&cslow[qh*NN + col], c);
    __syncthreads();       // drain all waves' stores
    if (tid == 0)
        __hip_atomic_fetch_add(&flags[F_SLOW(kt)], 1, __ATOMIC_RELEASE,
                               __HIP_MEMORY_SCOPE_AGENT);
}

__global__ void __launch_bounds__(512, 1) fused_kernel(
    const float* __restrict__ W, const float* __restrict__ b,
    const float* __restrict__ x, float* ws_f, int* flags, float* __restrict__ out) {
    const int bid = blockIdx.x;
    if (bid == 0) {
        solver_fn(W, b, x, ws_f, flags, out);
    } else if (bid <= 8) {
        crit_fn(W, ws_f, flags, bid - 1);
    } else {
        const int idx = bid - 9;           // 0..55
        slow_fn(W, ws_f, flags, 2 + idx/4, idx & 3);
    }
}

extern "C" void kernel_launch(void* const* d_in, const int* in_sizes, int n_in,
                              void* d_out, int out_size, void* d_ws, size_t ws_size,
                              hipStream_t stream) {
    const float* x = (const float*)d_in[0];
    const float* W = (const float*)d_in[1];
    const float* b = (const float*)d_in[2];
    float* out = (float*)d_out;
    float* ws_f = (float*)d_ws;
    int* flags  = (int*)d_ws;

    init_flags<<<dim3(1), dim3(256), 0, stream>>>(flags);
    fused_kernel<<<dim3(65), dim3(512), 0, stream>>>(W, b, x, ws_f, flags, out);
}

// Round 3
// 815.351 us; speedup vs baseline: 3.3724x; 3.3724x over previous
//
#include <hip/hip_runtime.h>

#define NN 8192
#define SBS 512    // super-block (grid-level) size
#define NSB 16     // number of super-blocks
#define SUB 64     // sub-block solved by one wave
#define LOG2E 1.44269504088896f

// d_ws layout (floats): cp[8][NN] | s_arr[NN]

__device__ __forceinline__ float bcastf(float v, int lane) {
    return __int_as_float(__builtin_amdgcn_readlane(__float_as_int(v), lane));
}

__global__ void init_kernel(float* cp) {
    int i = blockIdx.x * blockDim.x + threadIdx.x;
    if (i < 8 * NN) cp[i] = 0.0f;
}

// one WG, 8 waves; wave w owns cols [k*512 + w*64, +64)
__global__ void __launch_bounds__(512, 1) solve_kernel(
    const float* __restrict__ W, const float* __restrict__ b,
    const float* __restrict__ x, const float* __restrict__ cp,
    float* __restrict__ s_arr, float* __restrict__ out, int k)
{
    __shared__ float sscaled[SBS];    // log2e * s for this super-block
    const int tid = threadIdx.x;
    const int w = tid >> 6, l = tid & 63;
    const int J0 = k * SBS;
    const int col = J0 + w * SUB + l;

    // ---- issue all block-start loads immediately (latency hides under each other) ----
    const float bb = b[col];
    float cps[8];
    #pragma unroll
    for (int r = 0; r < 8; ++r) cps[r] = cp[r * NN + col];
    const float x0 = x[0], x1 = x[1];

    // own 64x64 strict-upper diagonal micro-block (pre-scaled by log2e)
    float wdiag[SUB];
    #pragma unroll
    for (int j = 0; j < SUB; ++j)
        wdiag[j] = (j < l) ? W[(size_t)(J0 + w * SUB + j) * NN + col] * LOG2E : 0.0f;

    // first fold panel (sub-block 0 rows) for waves w>0
    float pan[SUB];
    if (w > 0) {
        #pragma unroll
        for (int i = 0; i < SUB; ++i)
            pan[i] = W[(size_t)(J0 + i) * NN + col];
    }

    float base = bb;
    #pragma unroll
    for (int r = 0; r < 8; ++r) base += cps[r];
    float acc = base * LOG2E;    // pre-activation in log2e units
    float s_keep = 0.0f;

    #pragma unroll 1
    for (int m = 0; m < 8; ++m) {
        if (w == m) {
            // ---- the 64-step sequential sigmoid chain ----
            const bool first = (k == 0) && (m == 0);
            float smine = 0.0f;
            #pragma unroll
            for (int j = 0; j < SUB; ++j) {
                const float pre = bcastf(acc, j);
                float s;
                if (first && j == 0)      s = x0;
                else if (first && j == 1) s = x1;
                else s = __builtin_amdgcn_rcpf(1.0f + __builtin_amdgcn_exp2f(-pre));
                acc += wdiag[j] * s;     // wdiag[j]==0 for l<=j -> strict lower only
                if (l == j) smine = s;
            }
            sscaled[m * SUB + l] = smine * LOG2E;
            s_arr[J0 + m * SUB + l] = smine;
            s_keep = smine;
        }
        __syncthreads();
        if (m < w) {
            // fold published sub-block from registers + LDS broadcast
            #pragma unroll
            for (int i = 0; i < SUB; ++i)
                acc += pan[i] * sscaled[m * SUB + i];
            if (m + 1 < w) {
                // prefetch next panel; latency hides under wave m+1's chain
                #pragma unroll
                for (int i = 0; i < SUB; ++i)
                    pan[i] = W[(size_t)(J0 + (m + 1) * SUB + i) * NN + col];
            }
        }
    }
    if (k == NSB - 1 && w == 7 && l == 63) out[0] = s_keep;
}

// rank-512 right-looking update of all future columns, deterministic via
// 8 disjoint row-chunk partial accumulators
__global__ void __launch_bounds__(256) update_kernel(
    const float* __restrict__ W, const float* __restrict__ s_arr,
    float* __restrict__ cp, int k)
{
    __shared__ float ssh[SUB];
    const int tid = threadIdx.x;
    const int rc = blockIdx.y;
    const int row0 = k * SBS + rc * SUB;
    const int col = (k + 1) * SBS + blockIdx.x * 256 + tid;
    if (tid < SUB) ssh[tid] = s_arr[row0 + tid];
    __syncthreads();
    const float* wp = W + (size_t)row0 * NN + col;
    float a0 = 0.f, a1 = 0.f, a2 = 0.f, a3 = 0.f;
    #pragma unroll
    for (int i = 0; i < SUB; i += 4) {
        a0 += wp[(size_t)(i + 0) * NN] * ssh[i + 0];
        a1 += wp[(size_t)(i + 1) * NN] * ssh[i + 1];
        a2 += wp[(size_t)(i + 2) * NN] * ssh[i + 2];
        a3 += wp[(size_t)(i + 3) * NN] * ssh[i + 3];
    }
    cp[rc * NN + col] += (a0 + a1) + (a2 + a3);
}

extern "C" void kernel_launch(void* const* d_in, const int* in_sizes, int n_in,
                              void* d_out, int out_size, void* d_ws, size_t ws_size,
                              hipStream_t stream) {
    const float* x = (const float*)d_in[0];
    const float* W = (const float*)d_in[1];
    const float* b = (const float*)d_in[2];
    float* out = (float*)d_out;
    float* cp = (float*)d_ws;        // 8*NN floats
    float* s_arr = cp + 8 * NN;      // NN floats

    init_kernel<<<dim3((8 * NN) / 256), dim3(256), 0, stream>>>(cp);
    for (int k = 0; k < NSB; ++k) {
        solve_kernel<<<dim3(1), dim3(512), 0, stream>>>(W, b, x, cp, s_arr, out, k);
        if (k < NSB - 1) {
            int M = NN - (k + 1) * SBS;
            update_kernel<<<dim3(M / 256, 8), dim3(256), 0, stream>>>(W, s_arr, cp, k);
        }
    }
}

// Round 4
// 422.022 us; speedup vs baseline: 6.5155x; 1.9320x over previous
//
#include <hip/hip_runtime.h>

#define NN 8192
#define SBS 512
#define NSB 16
#define LOG2E 1.44269504088896f

// ws layout:
//   ints  : [0] = F_SUBDONE (monotone k*8+m+1), FR(k,w) at 32+(k*8+w)*32 ; region [0,8192)
//   floats: partials [8192,16384) ; cp [16384,81920) ; s_arr [81920,90112)
#define FR(k,w) (32 + ((k)*8 + (w))*32)
#define PART_OFF 8192
#define CP_OFF   16384
#define SARR_OFF 81920

__device__ __forceinline__ float bcastf(float v, int lane) {
    return __int_as_float(__builtin_amdgcn_readlane(__float_as_int(v), lane));
}
__device__ __forceinline__ float sigm(float prelog) {   // pre already in log2e units
    return __builtin_amdgcn_rcpf(1.0f + __builtin_amdgcn_exp2f(-prelog));
}
__device__ __forceinline__ int ld_flag(const int* p) {
    return __hip_atomic_load(p, __ATOMIC_RELAXED, __HIP_MEMORY_SCOPE_AGENT);
}
__device__ __forceinline__ void st_rel(int* p, int v) {
    __hip_atomic_store(p, v, __ATOMIC_RELEASE, __HIP_MEMORY_SCOPE_AGENT);
}
__device__ __forceinline__ float ldf(const float* p) {
    return __hip_atomic_load(p, __ATOMIC_RELAXED, __HIP_MEMORY_SCOPE_AGENT);
}
__device__ __forceinline__ void stf(float* p, float v) {
    __hip_atomic_store(p, v, __ATOMIC_RELAXED, __HIP_MEMORY_SCOPE_AGENT);
}
// barrier that does NOT drain vmcnt (keeps streamed prefetch loads in flight)
#define LBAR() do { asm volatile("s_waitcnt lgkmcnt(0)\ns_barrier" ::: "memory"); \
                    __builtin_amdgcn_sched_barrier(0); } while (0)

__global__ void init_ws(int* wsi, float* wsf) {
    int i = blockIdx.x * 256 + threadIdx.x;
    if (i < 8192) wsi[i] = 0;
    if (i < 65536) wsf[CP_OFF + i] = 0.0f;
}

// ---------- helper WG: target sub-block TW, folds sub-blocks 0..TW-2 of block k ----------
template <int TW>
__device__ void helper_fn(const float* __restrict__ W, float* wsf, int* flags,
                          float (*red)[8][64], int k) {
    const int tid = threadIdx.x, g = tid >> 6, l = tid & 63;
    float* partials = wsf + PART_OFF;
    const float* s_arr = wsf + SARR_OFF;
    const int J0 = k * SBS;

    float pr[TW - 1][8];
    #pragma unroll
    for (int m = 0; m < TW - 1; ++m)
        #pragma unroll
        for (int r = 0; r < 8; ++r)
            pr[m][r] = W[(size_t)(J0 + m*64 + g*8 + r) * NN + (J0 + TW*64 + l)];

    float part = 0.0f;
    #pragma unroll
    for (int m = 0; m <= TW - 2; ++m) {
        if (tid < 64) {
            while (ld_flag(&flags[0]) < k*8 + m + 1) __builtin_amdgcn_s_sleep(2);
        }
        __syncthreads();
        __builtin_amdgcn_fence(__ATOMIC_ACQUIRE, "agent");
        #pragma unroll
        for (int r = 0; r < 8; ++r)
            part += pr[m][r] * ldf(&s_arr[J0 + m*64 + g*8 + r]);
    }
    red[0][g][l] = part;
    __syncthreads();
    if (tid < 64) {
        float tot = 0.0f;
        #pragma unroll
        for (int g2 = 0; g2 < 8; ++g2) tot += red[0][g2][tid];
        stf(&partials[((size_t)k*8 + TW)*64 + tid], tot);
    }
    __syncthreads();
    if (tid == 0) st_rel(&flags[FR(k, TW)], 1);
}

// ---------- solver WG: 8 waves, wave w owns cols [k*512 + w*64, +64) ----------
__device__ void solver_fn(const float* __restrict__ W, const float* __restrict__ b,
                          const float* __restrict__ x, float* wsf, int* flags,
                          float* sdiag, float* spub, float* sacc,
                          float (*red)[8][64], float* __restrict__ out, int k) {
    const int tid = threadIdx.x;
    const int w = tid >> 6, l = tid & 63;
    const int dj = tid >> 3, dc = (tid & 7) * 8;   // diag staging role
    const int J0 = k * SBS;
    const float* cp = wsf + CP_OFF;
    float* partials = wsf + PART_OFF;
    float* s_arr = wsf + SARR_OFF;

    auto load_diag = [&](int mm, float4& a, float4& bq) {
        const float* p = &W[(size_t)(J0 + mm*64 + dj) * NN + (J0 + mm*64 + dc)];
        a  = *(const float4*)p;
        bq = *(const float4*)(p + 4);
    };
    auto write_diag = [&](int mm, float4 a, float4 bq) {
        float* dst = &sdiag[mm*4096 + dj*64 + dc];
        float v[8] = {a.x, a.y, a.z, a.w, bq.x, bq.y, bq.z, bq.w};
        #pragma unroll
        for (int e = 0; e < 8; ++e) dst[e] = (dj < dc + e) ? v[e] * LOG2E : 0.0f;
    };
    auto load_panel = [&](int mm, float* pr) {   // rows mm*64+w*8+r, col (mm+1)*64+l
        #pragma unroll
        for (int r = 0; r < 8; ++r)
            pr[r] = W[(size_t)(J0 + mm*64 + w*8 + r) * NN + (J0 + (mm+1)*64 + l)];
    };

    // ---- prologue: need-ordered issue ----
    const float x0 = x[0], x1 = x[1];
    float base = b[J0 + tid];
    #pragma unroll
    for (int r = 0; r < 8; ++r) base += cp[r * NN + J0 + tid];
    float4 dA[2], dB[2];
    load_diag(0, dA[0], dB[0]);
    load_diag(1, dA[1], dB[1]);
    float preg[2][8];
    load_panel(0, preg[0]);
    load_panel(1, preg[1]);
    write_diag(0, dA[0], dB[0]);
    write_diag(1, dA[1], dB[1]);
    sacc[tid] = base;
    LBAR();

    #pragma unroll
    for (int m = 0; m < 8; ++m) {
        if (w == m) {
            float part = 0.0f;
            if (m >= 2) {
                const int* fl = &flags[FR(k, m)];
                while (ld_flag(fl) == 0) {}
                __builtin_amdgcn_fence(__ATOMIC_ACQUIRE, "agent");
                part = ldf(&partials[((size_t)k*8 + m)*64 + l]);
            }
            float rsum = 0.0f;
            if (m >= 1) {
                #pragma unroll
                for (int g = 0; g < 8; ++g) rsum += red[(m-1) & 1][g][l];
            }
            float acc = (sacc[m*64 + l] + rsum + part) * LOG2E;
            float smine = 0.0f;
            const bool first = (k == 0) && (m == 0);
            #pragma unroll
            for (int j = 0; j < 64; ++j) {
                const float pre = bcastf(acc, j);
                float s;
                if (first && j == 0)      s = x0;
                else if (first && j == 1) s = x1;
                else                      s = sigm(pre);
                acc += sdiag[m*4096 + j*64 + l] * s;   // 0 for j>=l
                if (l == j) smine = s;
            }
            spub[m*64 + l] = smine;
            stf(&s_arr[J0 + m*64 + l], smine);
            if (k == NSB - 1 && m == 7 && l == 63) out[0] = smine;
            if (l == 0) st_rel(&flags[0], k*8 + m + 1);
        }
        LBAR();                                   // spub visible to fold
        if (m < 7) {
            // immediate fold m -> m+1 (panel regs prefetched 2 windows ago)
            float partial = 0.0f;
            #pragma unroll
            for (int r = 0; r < 8; ++r)
                partial += preg[m & 1][r] * spub[m*64 + w*8 + r];
            red[m & 1][w][l] = partial;
            // stage pipeline: write diag(m+1) (loaded last window), issue loads 2 ahead
            if (m >= 1) write_diag(m + 1, dA[(m+1) & 1], dB[(m+1) & 1]);
            if (m + 2 <= 7) load_diag(m + 2, dA[(m+2) & 1], dB[(m+2) & 1]);
            if (m + 2 <= 6) load_panel(m + 2, preg[m & 1]);
            LBAR();                               // red + diag writes visible
        }
    }
}

__global__ void __launch_bounds__(512, 1) solve_kernel(
    const float* __restrict__ W, const float* __restrict__ b,
    const float* __restrict__ x, float* wsf, int* flags,
    float* __restrict__ out, int k)
{
    __shared__ float sdiag[8 * 4096];   // [m][j][l], pre-scaled by LOG2E, 0 for j>=l
    __shared__ float spub[512];         // s (natural) of this block
    __shared__ float sacc[512];         // base pre-activation (b + cp)
    __shared__ float red[2][8][64];     // immediate-fold partials (dbuf)
    const int bid = blockIdx.x;
    if (bid == 0) {
        solver_fn(W, b, x, wsf, flags, sdiag, spub, sacc, red, out, k);
    } else {
        switch (bid) {
            case 1: helper_fn<2>(W, wsf, flags, red, k); break;
            case 2: helper_fn<3>(W, wsf, flags, red, k); break;
            case 3: helper_fn<4>(W, wsf, flags, red, k); break;
            case 4: helper_fn<5>(W, wsf, flags, red, k); break;
            case 5: helper_fn<6>(W, wsf, flags, red, k); break;
            case 6: helper_fn<7>(W, wsf, flags, red, k); break;
        }
    }
}

// rank-512 inter-block update, deterministic via 8 disjoint row-chunk partials
__global__ void __launch_bounds__(256) update_kernel(
    const float* __restrict__ W, const float* __restrict__ wsf_s,
    float* __restrict__ cp, int k)
{
    __shared__ float ssh[64];
    const int tid = threadIdx.x;
    const int rc = blockIdx.y;
    const int row0 = k * SBS + rc * 64;
    const int col = (k + 1) * SBS + blockIdx.x * 256 + tid;
    if (tid < 64) ssh[tid] = wsf_s[row0 + tid];
    __syncthreads();
    const float* wp = W + (size_t)row0 * NN + col;
    float a0 = 0.f, a1 = 0.f, a2 = 0.f, a3 = 0.f;
    #pragma unroll
    for (int i = 0; i < 64; i += 4) {
        a0 += wp[(size_t)(i + 0) * NN] * ssh[i + 0];
        a1 += wp[(size_t)(i + 1) * NN] * ssh[i + 1];
        a2 += wp[(size_t)(i + 2) * NN] * ssh[i + 2];
        a3 += wp[(size_t)(i + 3) * NN] * ssh[i + 3];
    }
    cp[rc * NN + col] += (a0 + a1) + (a2 + a3);
}

extern "C" void kernel_launch(void* const* d_in, const int* in_sizes, int n_in,
                              void* d_out, int out_size, void* d_ws, size_t ws_size,
                              hipStream_t stream) {
    const float* x = (const float*)d_in[0];
    const float* W = (const float*)d_in[1];
    const float* b = (const float*)d_in[2];
    float* out = (float*)d_out;
    float* wsf = (float*)d_ws;
    int* wsi   = (int*)d_ws;
    float* cp    = wsf + CP_OFF;
    float* s_arr = wsf + SARR_OFF;

    init_ws<<<dim3(256), dim3(256), 0, stream>>>(wsi, wsf);
    for (int k = 0; k < NSB; ++k) {
        solve_kernel<<<dim3(7), dim3(512), 0, stream>>>(W, b, x, wsf, wsi, out, k);
        if (k < NSB - 1) {
            int M = NN - (k + 1) * SBS;
            update_kernel<<<dim3(M / 256, 8), dim3(256), 0, stream>>>(W, s_arr, cp, k);
        }
    }
}

// Round 5
// 411.705 us; speedup vs baseline: 6.6788x; 1.0251x over previous
//
#include <hip/hip_runtime.h>

#define NN 8192
#define SBS 512
#define NSB 16
#define LOG2E 1.44269504088896f

// ws ints: [0]=F_SUBDONE (monotone k*8+m+1); FR(k,w) per-(k,target) lines
#define FR(k,w) (32 + ((k)*8 + (w))*32)
// ws floats: partials [8192,16384) | cp[9][NN] [16384,90112) | s_arr [90112,98304)
#define PART_OFF 8192
#define CP_OFF   16384
#define NCPROW   9
#define SARR_OFF (CP_OFF + NCPROW * NN)

__device__ __forceinline__ float bcastf(float v, int lane) {
    return __int_as_float(__builtin_amdgcn_readlane(__float_as_int(v), lane));
}
__device__ __forceinline__ float sigm(float prelog) {   // pre already in log2e units
    return __builtin_amdgcn_rcpf(1.0f + __builtin_amdgcn_exp2f(-prelog));
}
__device__ __forceinline__ int ld_flag(const int* p) {
    return __hip_atomic_load(p, __ATOMIC_RELAXED, __HIP_MEMORY_SCOPE_AGENT);
}
__device__ __forceinline__ void st_rel(int* p, int v) {
    __hip_atomic_store(p, v, __ATOMIC_RELEASE, __HIP_MEMORY_SCOPE_AGENT);
}
__device__ __forceinline__ float ldf(const float* p) {
    return __hip_atomic_load(p, __ATOMIC_RELAXED, __HIP_MEMORY_SCOPE_AGENT);
}
__device__ __forceinline__ void stf(float* p, float v) {
    __hip_atomic_store(p, v, __ATOMIC_RELAXED, __HIP_MEMORY_SCOPE_AGENT);
}
// barrier that does NOT drain vmcnt (keeps streamed prefetch loads in flight)
#define LBAR() do { asm volatile("s_waitcnt lgkmcnt(0)\ns_barrier" ::: "memory"); \
                    __builtin_amdgcn_sched_barrier(0); } while (0)

__global__ void init_ws(int* wsi, float* wsf) {
    int i = blockIdx.x * 256 + threadIdx.x;   // grid 288*256 = 73728 = 9*NN
    if (i < 8192) wsi[i] = 0;
    wsf[CP_OFF + i] = 0.0f;
}

// ---------- solver WG: 8 waves; wave w owns cols [k*512 + w*64, +64) ----------
__device__ void solver_fn(const float* __restrict__ W, const float* __restrict__ b,
                          const float* __restrict__ x, float* wsf, int* flags,
                          float* sdiag, float* spub, float* sacc,
                          float (*redN)[8][64], float (*redF)[8][64],
                          float* __restrict__ out, int k) {
    const int tid = threadIdx.x;
    const int w = tid >> 6, l = tid & 63;
    const int dj = tid >> 3, dc = (tid & 7) * 8;   // diag staging role
    const int J0 = k * SBS;
    const float* cp = wsf + CP_OFF;
    float* partials = wsf + PART_OFF;
    float* s_arr = wsf + SARR_OFF;

    auto load_diag = [&](int mm, float4& a, float4& bq) {
        const float* p = &W[(size_t)(J0 + mm*64 + dj) * NN + (J0 + mm*64 + dc)];
        a  = *(const float4*)p;
        bq = *(const float4*)(p + 4);
    };
    auto write_diag = [&](int mm, float4 a, float4 bq) {
        float* dst = &sdiag[mm*4096 + dj*64 + dc];
        float v[8] = {a.x, a.y, a.z, a.w, bq.x, bq.y, bq.z, bq.w};
        #pragma unroll
        for (int e = 0; e < 8; ++e) dst[e] = (dj < dc + e) ? v[e] * LOG2E : 0.0f;
    };
    auto load_pan1 = [&](int mm, float* pr) {   // source mm -> target mm+1
        #pragma unroll
        for (int r = 0; r < 8; ++r)
            pr[r] = W[(size_t)(J0 + mm*64 + w*8 + r) * NN + (J0 + (mm+1)*64 + l)];
    };
    auto load_pan2 = [&](int mm, float* pr) {   // source mm -> target mm+2
        #pragma unroll
        for (int r = 0; r < 8; ++r)
            pr[r] = W[(size_t)(J0 + mm*64 + w*8 + r) * NN + (J0 + (mm+2)*64 + l)];
    };

    // ---- prologue: need-ordered issue ----
    const float x0 = x[0], x1 = x[1];
    float base = b[J0 + tid];
    #pragma unroll
    for (int r = 0; r < NCPROW; ++r) base += cp[r * NN + J0 + tid];
    float4 dA[2], dB[2];
    load_diag(0, dA[0], dB[0]);
    load_diag(1, dA[1], dB[1]);
    float p1[2][8], p2[2][8];
    load_pan1(0, p1[0]);
    load_pan1(1, p1[1]);
    load_pan2(0, p2[0]);
    load_pan2(1, p2[1]);
    write_diag(0, dA[0], dB[0]);
    write_diag(1, dA[1], dB[1]);
    sacc[tid] = base;
    redF[1][w][l] = 0.0f;       // wave 1 reads redF[1]; no distance-2 source exists
    LBAR();

    #pragma unroll
    for (int m = 0; m < 8; ++m) {
        if (w == m) {
            float part = 0.0f;
            if (m >= 3) {                       // helper contribution (distance >= 3)
                const int* fl = &flags[FR(k, m)];
                while (ld_flag(fl) == 0) {}
                __builtin_amdgcn_fence(__ATOMIC_ACQUIRE, "agent");
                part = ldf(&partials[((size_t)k*8 + m)*64 + l]);
            }
            float rsum = 0.0f;
            if (m >= 1) {
                #pragma unroll
                for (int g = 0; g < 8; ++g) rsum += redN[m & 1][g][l];
            }
            if (m >= 2) {
                #pragma unroll
                for (int g = 0; g < 8; ++g) rsum += redF[m & 1][g][l];
            }
            float acc = (sacc[m*64 + l] + rsum + part) * LOG2E;
            float smine = 0.0f;
            const bool first = (k == 0) && (m == 0);
            #pragma unroll
            for (int j = 0; j < 64; ++j) {
                const float pre = bcastf(acc, j);
                float s;
                if (first && j == 0)      s = x0;
                else if (first && j == 1) s = x1;
                else                      s = sigm(pre);
                acc += sdiag[m*4096 + j*64 + l] * s;   // 0 for j>=l
                if (l == j) smine = s;
            }
            spub[m*64 + l] = smine;
            stf(&s_arr[J0 + m*64 + l], smine);
            if (k == NSB - 1 && m == 7 && l == 63) out[0] = smine;
            if (l == 0) st_rel(&flags[0], k*8 + m + 1);
        }
        LBAR();                                   // spub visible to folds
        if (m < 7) {
            // local distance-1 fold: source m -> target m+1
            float f1 = 0.0f;
            #pragma unroll
            for (int r = 0; r < 8; ++r)
                f1 += p1[m & 1][r] * spub[m*64 + w*8 + r];
            redN[(m+1) & 1][w][l] = f1;
            // local distance-2 fold: source m -> target m+2
            if (m < 6) {
                float f2 = 0.0f;
                #pragma unroll
                for (int r = 0; r < 8; ++r)
                    f2 += p2[m & 1][r] * spub[m*64 + w*8 + r];
                redF[m & 1][w][l] = f2;
            }
            // staging pipeline (2-window)
            if (m >= 1) write_diag(m + 1, dA[(m+1) & 1], dB[(m+1) & 1]);
            if (m + 2 <= 7) load_diag(m + 2, dA[(m+2) & 1], dB[(m+2) & 1]);
            if (m + 2 <= 6) load_pan1(m + 2, p1[m & 1]);
            if (m + 2 <= 5) load_pan2(m + 2, p2[m & 1]);
            LBAR();                               // red + diag writes visible
        }
    }
}

// ---------- helper WG: target TW (>=3), folds sources 0..TW-3 ----------
template <int TW>
__device__ void helper_fn(const float* __restrict__ W, float* wsf, int* flags,
                          float (*redh)[64], int k) {
    const int tid = threadIdx.x, g = tid >> 6, l = tid & 63;
    float* partials = wsf + PART_OFF;
    const float* s_arr = wsf + SARR_OFF;
    const int J0 = k * SBS;

    float pr[TW - 2][8];
    #pragma unroll
    for (int m = 0; m <= TW - 3; ++m)
        #pragma unroll
        for (int r = 0; r < 8; ++r)
            pr[m][r] = W[(size_t)(J0 + m*64 + g*8 + r) * NN + (J0 + TW*64 + l)];

    float part = 0.0f;
    #pragma unroll
    for (int m = 0; m <= TW - 3; ++m) {
        if (tid < 64) {
            while (ld_flag(&flags[0]) < k*8 + m + 1) __builtin_amdgcn_s_sleep(2);
        }
        __syncthreads();
        __builtin_amdgcn_fence(__ATOMIC_ACQUIRE, "agent");
        #pragma unroll
        for (int r = 0; r < 8; ++r)
            part += pr[m][r] * ldf(&s_arr[J0 + m*64 + g*8 + r]);
    }
    redh[g][l] = part;
    __syncthreads();
    if (tid < 64) {
        float tot = 0.0f;
        #pragma unroll
        for (int g2 = 0; g2 < 8; ++g2) tot += redh[g2][tid];
        stf(&partials[((size_t)k*8 + TW)*64 + tid], tot);
    }
    __syncthreads();
    if (tid == 0) st_rel(&flags[FR(k, TW)], 1);
}

// ---------- near WG: block k -> block k+1, target sub-block t (progressive) ----------
__device__ void near_fn(const float* __restrict__ W, float* wsf, int* flags,
                        float (*redh)[64], int t, int k) {
    const int tid = threadIdx.x, g = tid >> 6, l = tid & 63;
    const int col = (k+1)*SBS + t*64 + l;
    const float* s_arr = wsf + SARR_OFF;
    float* cp = wsf + CP_OFF;

    float pr[8][8];
    #pragma unroll
    for (int m = 0; m < 8; ++m)
        #pragma unroll
        for (int r = 0; r < 8; ++r)
            pr[m][r] = W[(size_t)(k*SBS + m*64 + g*8 + r) * NN + col];

    float part = 0.0f;
    #pragma unroll
    for (int m = 0; m < 8; ++m) {
        if (tid < 64) {
            while (ld_flag(&flags[0]) < k*8 + m + 1) __builtin_amdgcn_s_sleep(4);
        }
        __syncthreads();
        __builtin_amdgcn_fence(__ATOMIC_ACQUIRE, "agent");
        #pragma unroll
        for (int r = 0; r < 8; ++r)
            part += pr[m][r] * ldf(&s_arr[k*SBS + m*64 + g*8 + r]);
    }
    redh[g][l] = part;
    __syncthreads();
    if (g == 0) {
        float tot = 0.0f;
        #pragma unroll
        for (int g2 = 0; g2 < 8; ++g2) tot += redh[g2][l];
        cp[8 * NN + col] = tot;           // 9th accumulator row: near-only, fresh write
    }
}

// ---------- bulk WG: source block k-1 -> targets k+1..15 (inputs all ready) ----------
__device__ void bulk_fn(const float* __restrict__ W, float* wsf,
                        float* ssh, int idx, int k) {
    const int tid = threadIdx.x;
    const int rc = idx & 7, cg = idx >> 3;
    const int row0 = (k-1)*SBS + rc*64;
    const int col = (k+1)*SBS + cg*SBS + tid;
    const float* s_arr = wsf + SARR_OFF;
    float* cp = wsf + CP_OFF;

    if (tid < 64) ssh[tid] = s_arr[row0 + tid];
    __syncthreads();
    const float* wp = W + (size_t)row0 * NN + col;
    float a0 = 0.f, a1 = 0.f, a2 = 0.f, a3 = 0.f;
    #pragma unroll
    for (int i = 0; i < 64; i += 4) {
        a0 += wp[(size_t)(i + 0) * NN] * ssh[i + 0];
        a1 += wp[(size_t)(i + 1) * NN] * ssh[i + 1];
        a2 += wp[(size_t)(i + 2) * NN] * ssh[i + 2];
        a3 += wp[(size_t)(i + 3) * NN] * ssh[i + 3];
    }
    cp[rc * NN + col] += (a0 + a1) + (a2 + a3);   // single writer per (rc,col) per launch
}

__global__ void __launch_bounds__(512, 1) mega_kernel(
    const float* __restrict__ W, const float* __restrict__ b,
    const float* __restrict__ x, float* wsf, int* flags,
    float* __restrict__ out, int k)
{
    __shared__ float sdiag[8 * 4096];   // [m][j][l], pre-scaled by LOG2E, 0 for j>=l
    __shared__ float spub[512];
    __shared__ float sacc[512];
    __shared__ float redN[2][8][64];    // distance-1 fold partials
    __shared__ float redF[2][8][64];    // distance-2 fold partials
    __shared__ float redh[8][64];       // helper/near reduction, bulk s staging
    const int bid = blockIdx.x;
    if (bid == 0) {
        solver_fn(W, b, x, wsf, flags, sdiag, spub, sacc, redN, redF, out, k);
    } else if (bid <= 5) {
        switch (bid) {
            case 1: helper_fn<3>(W, wsf, flags, redh, k); break;
            case 2: helper_fn<4>(W, wsf, flags, redh, k); break;
            case 3: helper_fn<5>(W, wsf, flags, redh, k); break;
            case 4: helper_fn<6>(W, wsf, flags, redh, k); break;
            case 5: helper_fn<7>(W, wsf, flags, redh, k); break;
        }
    } else if (bid <= 13) {
        near_fn(W, wsf, flags, redh, bid - 6, k);     // grid excludes these at k=15
    } else {
        bulk_fn(W, wsf, &redh[0][0], bid - 14, k);    // grid nonzero only for k>=1
    }
}

extern "C" void kernel_launch(void* const* d_in, const int* in_sizes, int n_in,
                              void* d_out, int out_size, void* d_ws, size_t ws_size,
                              hipStream_t stream) {
    const float* x = (const float*)d_in[0];
    const float* W = (const float*)d_in[1];
    const float* b = (const float*)d_in[2];
    float* out = (float*)d_out;
    float* wsf = (float*)d_ws;
    int* wsi   = (int*)d_ws;

    init_ws<<<dim3(288), dim3(256), 0, stream>>>(wsi, wsf);
    for (int k = 0; k < NSB; ++k) {
        int nb;
        if (k == 0)            nb = 14;                     // solver + 5 helpers + 8 near
        else if (k == NSB - 1) nb = 6;                      // solver + 5 helpers
        else                   nb = 14 + (15 - k) * 8;      // + bulk (src k-1 -> k+1..15)
        mega_kernel<<<dim3(nb), dim3(512), 0, stream>>>(W, b, x, wsf, wsi, out, k);
    }
}